// Round 6
// baseline (115.323 us; speedup 1.0000x reference)
//
#include <hip/hip_runtime.h>
#include <stdint.h>

// NaiveBias (symmetric Toeplitz bias contraction): out[b,j,h,d] = sum_l w[h,|l-j|] * v[b,l,h,d]
// B=2, S=2048, H=16, D=64, fp32 in/out.
// R6: R4 structure with the tab-read race fixed (initial load_afrag AFTER first barrier).
// Single-barrier-per-tile double-buffered pipeline, trunc-hi split, setprio on MFMA.
// Per (b,h): C(2048x64) = T(2048x2048 Toeplitz) @ V(2048x64), mfma_f32_16x16x32_bf16,
// 3-term bf16 hi/lo split (Thi*Vhi + Thi*Vlo + Tlo*Vhi) for fp32-grade accuracy.

#define SS 2048
#define HH 16
#define DD 64

typedef uint32_t u32;
typedef uint16_t u16;
typedef __attribute__((ext_vector_type(8))) short bf16x8;
typedef __attribute__((ext_vector_type(4))) float f32x4;

__device__ __forceinline__ u16 f2bf(float x) {
  u32 u = __float_as_uint(x);
  u = u + 0x7fffu + ((u >> 16) & 1u);   // RNE truncate to bf16
  return (u16)(u >> 16);
}
__device__ __forceinline__ float bf2f(u16 h) {
  return __uint_as_float(((u32)h) << 16);
}
__device__ __forceinline__ void bfsplit(float x, u16& hi, u16& lo) {
  hi = f2bf(x);
  lo = f2bf(x - bf2f(hi));
}

// packed split of 2 floats: hi = bit-truncate (exact residual), lo = RNE(residual).
// x = hi + lo + err, |err| <= 2^-17 |x|. ph/pl hold {x0,x1} as packed bf16 pairs.
__device__ __forceinline__ void split2(float x0, float x1, u32& ph, u32& pl) {
  u32 u0 = __float_as_uint(x0), u1 = __float_as_uint(x1);
  float h0 = __uint_as_float(u0 & 0xffff0000u);
  float h1 = __uint_as_float(u1 & 0xffff0000u);
  ph = __builtin_amdgcn_perm(u1, u0, 0x07060302u);   // {u1.hi16, u0.hi16}
  u32 v0 = __float_as_uint(x0 - h0); v0 += 0x7fffu + ((v0 >> 16) & 1u);
  u32 v1 = __float_as_uint(x1 - h1); v1 += 0x7fffu + ((v1 >> 16) & 1u);
  pl = __builtin_amdgcn_perm(v1, v0, 0x07060302u);
}

// ---------------- pre-pass: packed Toeplitz table  upk[h][t] = {hi,lo}(w[h][|2047-t|]) ----------------
__global__ __launch_bounds__(256) void prep_w(const float* __restrict__ w, u32* __restrict__ upk)
{
  const int h = blockIdx.x;
  const int t = blockIdx.y * 256 + threadIdx.x;   // 0..4095
  int r = 2047 - t;
  int idx = r < 0 ? -r : r;
  if (idx > 2047) idx = 2047;                     // t=4095 unused
  float x = w[h * SS + idx];
  u16 hi, lo; bfsplit(x, hi, lo);
  upk[h * 4096 + t] = (u32)hi | ((u32)lo << 16);
}

// unpack 8 packed dwords -> hi/lo bf16x8 fragments
__device__ __forceinline__ void load_afrag(const u32* tab, int t0, bf16x8& hi, bf16x8& lo) {
  u32 d0 = tab[t0 + 0], d1 = tab[t0 + 1], d2 = tab[t0 + 2], d3 = tab[t0 + 3];
  u32 d4 = tab[t0 + 4], d5 = tab[t0 + 5], d6 = tab[t0 + 6], d7 = tab[t0 + 7];
  union { u32 u[4]; bf16x8 v; } H, L;
  H.u[0] = __builtin_amdgcn_perm(d1, d0, 0x05040100u);  // lo16 halves -> hi frag
  H.u[1] = __builtin_amdgcn_perm(d3, d2, 0x05040100u);
  H.u[2] = __builtin_amdgcn_perm(d5, d4, 0x05040100u);
  H.u[3] = __builtin_amdgcn_perm(d7, d6, 0x05040100u);
  L.u[0] = __builtin_amdgcn_perm(d1, d0, 0x07060302u);  // hi16 halves -> lo frag
  L.u[1] = __builtin_amdgcn_perm(d3, d2, 0x07060302u);
  L.u[2] = __builtin_amdgcn_perm(d5, d4, 0x07060302u);
  L.u[3] = __builtin_amdgcn_perm(d7, d6, 0x07060302u);
  hi = H.v; lo = L.v;
}

// rotate Toeplitz shift-reuse (frag(jf,s+1) = frag(jf-2,s)) and load the 2 fresh pairs for l-base tnext
__device__ __forceinline__ void advance_frags(const u32* tab, int tnext, bf16x8 Ahi[4], bf16x8 Alo[4]) {
  Ahi[2] = Ahi[0]; Alo[2] = Alo[0];
  Ahi[3] = Ahi[1]; Alo[3] = Alo[1];
  load_afrag(tab, tnext,      Ahi[0], Alo[0]);
  load_afrag(tab, tnext - 16, Ahi[1], Alo[1]);
}

__device__ __forceinline__ void split_write(const float r[8], u16* wb) {
  u32 ph[4], pl[4];
  #pragma unroll
  for (int i = 0; i < 4; ++i) split2(r[2 * i], r[2 * i + 1], ph[i], pl[i]);
  *(uint4*)wb          = *(const uint4*)ph;
  *(uint4*)(wb + 2048) = *(const uint4*)pl;   // lo plane (+64*32 u16)
}

__device__ __forceinline__ void mma_tile(const u16* vb, int bro,
                                         const bf16x8 Ahi[4], const bf16x8 Alo[4],
                                         f32x4 acc[4][4]) {
  __builtin_amdgcn_s_setprio(1);
  #pragma unroll
  for (int nf = 0; nf < 4; ++nf) {
    bf16x8 bhf = *(const bf16x8*)(vb + nf * 512 + bro);
    bf16x8 blf = *(const bf16x8*)(vb + 2048 + nf * 512 + bro);
    #pragma unroll
    for (int jf = 0; jf < 4; ++jf) {
      acc[jf][nf] = __builtin_amdgcn_mfma_f32_16x16x32_bf16(Ahi[jf], bhf, acc[jf][nf], 0, 0, 0);
      acc[jf][nf] = __builtin_amdgcn_mfma_f32_16x16x32_bf16(Ahi[jf], blf, acc[jf][nf], 0, 0, 0);
      acc[jf][nf] = __builtin_amdgcn_mfma_f32_16x16x32_bf16(Alo[jf], bhf, acc[jf][nf], 0, 0, 0);
    }
  }
  __builtin_amdgcn_s_setprio(0);
}

// ---------------- fused main: per (b,h) Toeplitz GEMM, 8 waves, K-split halves ----------------
__global__ __launch_bounds__(512, 2) void toeplitz_fused(
    const float* __restrict__ v, const u32* __restrict__ upk, float* __restrict__ out)
{
  __shared__ __align__(16) u32 tab[4096];               // 16 KB packed Toeplitz table
  __shared__ __align__(16) u16 vt[2][2][2][64][32];     // [khalf][dbuf][hi/lo][d][l] 32 KB
  __shared__ __align__(16) float red4[4][64][16];       // 16 KB cross-half reduction

  const int tid  = threadIdx.x;
  const int lane = tid & 63;
  const int wv   = tid >> 6;        // 0..7
  const int half = wv >> 2;         // K-half: l in [half*1024, half*1024+1024)
  const int oct  = wv & 3;          // j-subtile index AND staging l-octet
  const int m    = lane & 15;       // MFMA row/col within fragment
  const int g    = lane >> 4;       // MFMA k-group

  // XCD-aware bijective swizzle: 4 (b,h) panels per XCD (2 MB fp32 < 4 MiB L2)
  const int lin = blockIdx.x;       // 0..255
  const int xcd = lin & 7;
  const int sl  = lin >> 3;         // 0..31
  const int bh  = (xcd << 2) | (sl >> 3);
  const int jt  = sl & 7;           // j-tile (256 rows)
  const int b = bh >> 4, h = bh & 15;

  // stage Toeplitz table (first barrier covers it)
  {
    const u32* src = upk + h * 4096;
    *(uint4*)&tab[tid * 4]        = *(const uint4*)&src[tid * 4];
    *(uint4*)&tab[2048 + tid * 4] = *(const uint4*)&src[2048 + tid * 4];
  }

  // staging geometry: thread stages row d=lane, l-octet oct, of its own half
  const int sd = lane;
  const int sslot = oct ^ ((sd >> 2) & 3);              // bank-balanced granule slot
  u16* wb0 = &vt[half][0][0][sd][sslot * 8];
  u16* wb1 = &vt[half][1][0][sd][sslot * 8];
  const float* gsrc = v + (((size_t)b * SS + half * 1024 + oct * 8) * HH + h) * DD + sd;
  // l-stride in floats = HH*DD = 1024; one K-tile (32 l) = 32768 floats

  // B-frag read offset (u16 elems): row m (+16*nf), granule g with matching swizzle
  const int bro = m * 32 + ((g ^ ((m >> 2) & 3)) << 3);

  // A (Toeplitz) base: t = 2047 - j + l
  const int jb = jt * 256 + oct * 64;
  const int tA = 2047 - jb - m + 8 * g + half * 1024;

  // ---- prologue: tile0 staged, tile1 in flight ----
  float rX[8], rY[8];
  #pragma unroll
  for (int i = 0; i < 8; ++i) rX[i] = gsrc[i * 1024];           // tile 0
  #pragma unroll
  for (int i = 0; i < 8; ++i) rY[i] = gsrc[32768 + i * 1024];   // tile 1
  split_write(rX, wb0);

  f32x4 acc[4][4];
  #pragma unroll
  for (int i = 0; i < 4; ++i)
    #pragma unroll
    for (int j = 0; j < 4; ++j)
      acc[i][j] = (f32x4)(0.0f);

  __syncthreads();   // tab + tile0 visible

  // initial A-frags: MUST be after the barrier (tab is written by all threads)
  bf16x8 Ahi[4], Alo[4];
  #pragma unroll
  for (int jf = 0; jf < 4; ++jf)
    load_afrag(tab, tA - 16 * jf, Ahi[jf], Alo[jf]);

  // ---- main loop: 2 tiles per su, ONE barrier per tile ----
  for (int su = 0; su < 16; ++su) {
    const int s0 = 2 * su;
    // EVEN: compute tile s0 (buf0); split rY(tile s0+1)->buf1; prefetch rX<-tile s0+2
    if (su < 15) {
      const float* gs = gsrc + (size_t)(s0 + 2) * 32768;
      #pragma unroll
      for (int i = 0; i < 8; ++i) rX[i] = gs[i * 1024];
    }
    split_write(rY, wb1);
    mma_tile(&vt[half][0][0][0][0], bro, Ahi, Alo, acc);
    advance_frags(tab, tA + 32 * (s0 + 1), Ahi, Alo);
    __syncthreads();

    // ODD: compute tile s0+1 (buf1); split rX(tile s0+2)->buf0; prefetch rY<-tile s0+3
    if (su < 15) {
      const float* gs = gsrc + (size_t)(s0 + 3) * 32768;
      #pragma unroll
      for (int i = 0; i < 8; ++i) rY[i] = gs[i * 1024];
      split_write(rX, wb0);
    }
    mma_tile(&vt[half][1][0][0][0], bro, Ahi, Alo, acc);
    if (su < 15) advance_frags(tab, tA + 32 * (s0 + 2), Ahi, Alo);
    __syncthreads();
  }

  // ---- cross-half reduction + store: wave oct(half1) pairs with oct(half0), same jb ----
  #pragma unroll
  for (int jf = 0; jf < 4; ++jf) {
    if (half == 1) {
      #pragma unroll
      for (int nf = 0; nf < 4; ++nf)
        *(f32x4*)&red4[oct][lane][nf * 4] = acc[jf][nf];
    }
    __syncthreads();
    if (half == 0) {
      #pragma unroll
      for (int nf = 0; nf < 4; ++nf) {
        f32x4 c = acc[jf][nf] + *(const f32x4*)&red4[oct][lane][nf * 4];
        #pragma unroll
        for (int q = 0; q < 4; ++q) {
          int j = jb + jf * 16 + g * 4 + q;
          int d = nf * 16 + m;
          out[(((size_t)b * SS + j) * HH + h) * DD + d] = c[q];
        }
      }
    }
    __syncthreads();
  }
}

// ---------------- fallback (tiny ws): direct fp32 VALU, correct but slow ----------------
__global__ __launch_bounds__(256) void fallback_k(const float* __restrict__ v,
                                                  const float* __restrict__ w,
                                                  float* __restrict__ out)
{
  __shared__ float wrow[SS];
  const int t = threadIdx.x;
  const int j0 = blockIdx.x * 64;
  const int bh = blockIdx.y;
  const int b = bh >> 4, h = bh & 15;
  for (int i = t; i < SS; i += 256) wrow[i] = w[h * SS + i];
  __syncthreads();
  const int jj = t >> 6, d = t & 63;
  float acc[16];
  #pragma unroll
  for (int r = 0; r < 16; ++r) acc[r] = 0.f;
  for (int l = 0; l < SS; ++l) {
    float vv = v[(((size_t)b * SS + l) * HH + h) * DD + d];
    #pragma unroll
    for (int r = 0; r < 16; ++r) {
      int dj = l - (j0 + jj * 16 + r);
      acc[r] += wrow[dj < 0 ? -dj : dj] * vv;
    }
  }
  #pragma unroll
  for (int r = 0; r < 16; ++r)
    out[(((size_t)b * SS + (j0 + jj * 16 + r)) * HH + h) * DD + d] = acc[r];
}

extern "C" void kernel_launch(void* const* d_in, const int* in_sizes, int n_in,
                              void* d_out, int out_size, void* d_ws, size_t ws_size,
                              hipStream_t stream)
{
  const float* v = (const float*)d_in[0];
  const float* w = (const float*)d_in[1];
  float* out = (float*)d_out;
  const size_t need = (size_t)HH * 4096 * 4;   // 256 KB packed Toeplitz table
  if (ws_size >= need) {
    u32* upk = (u32*)d_ws;
    prep_w<<<dim3(16, 16), 256, 0, stream>>>(w, upk);
    toeplitz_fused<<<dim3(256), 512, 0, stream>>>(v, upk, out);
  } else {
    fallback_k<<<dim3(32, 32), 256, 0, stream>>>(v, w, out);
  }
}

// Round 11
// 109.151 us; speedup vs baseline: 1.0565x; 1.0565x over previous
//
#include <hip/hip_runtime.h>
#include <stdint.h>

// NaiveBias (symmetric Toeplitz bias contraction): out[b,j,h,d] = sum_l w[h,|l-j|] * v[b,l,h,d]
// B=2, S=2048, H=16, D=64, fp32 in/out.
// R7..R11: 2-term split (Thi*Vbf + Tlo*Vbf), wave tile 128j x 64d, conflict-free LDS layouts,
// 2-barrier-per-tile structure (measured better than 1-barrier dbuf), no setprio.
// Error budget: max |err| ~5e-3 << 0.0156 tolerance (3x margin).

#define SS 2048
#define HH 16
#define DD 64

typedef uint32_t u32;
typedef uint16_t u16;
typedef __attribute__((ext_vector_type(8))) short bf16x8;
typedef __attribute__((ext_vector_type(4))) float f32x4;

__device__ __forceinline__ u16 f2bf(float x) {
  u32 u = __float_as_uint(x);
  u = u + 0x7fffu + ((u >> 16) & 1u);   // RNE to bf16
  return (u16)(u >> 16);
}
__device__ __forceinline__ float bf2f(u16 h) {
  return __uint_as_float(((u32)h) << 16);
}
__device__ __forceinline__ void bfsplit(float x, u16& hi, u16& lo) {
  hi = f2bf(x);
  lo = f2bf(x - bf2f(hi));   // exact residual; |x - hi - lo| <= ~2^-17 |x|
}

// ---------------- pre-pass: packed Toeplitz table  upk[h][t] = {hi,lo}(w[h][|2047-t|]) ----------------
__global__ __launch_bounds__(256) void prep_w(const float* __restrict__ w, u32* __restrict__ upk)
{
  const int h = blockIdx.x;
  const int t = blockIdx.y * 256 + threadIdx.x;   // 0..4095
  int r = 2047 - t;
  int idx = r < 0 ? -r : r;
  if (idx > 2047) idx = 2047;                     // t=4095 unused
  float x = w[h * SS + idx];
  u16 hi, lo; bfsplit(x, hi, lo);
  upk[h * 4096 + t] = (u32)hi | ((u32)lo << 16);
}

// unpack 8 packed dwords -> hi/lo bf16x8 fragments
__device__ __forceinline__ void load_afrag(const u32* tab, int t0, bf16x8& hi, bf16x8& lo) {
  u32 d0 = tab[t0 + 0], d1 = tab[t0 + 1], d2 = tab[t0 + 2], d3 = tab[t0 + 3];
  u32 d4 = tab[t0 + 4], d5 = tab[t0 + 5], d6 = tab[t0 + 6], d7 = tab[t0 + 7];
  union { u32 u[4]; bf16x8 v; } H, L;
  H.u[0] = __builtin_amdgcn_perm(d1, d0, 0x05040100u);  // lo16 halves -> hi frag
  H.u[1] = __builtin_amdgcn_perm(d3, d2, 0x05040100u);
  H.u[2] = __builtin_amdgcn_perm(d5, d4, 0x05040100u);
  H.u[3] = __builtin_amdgcn_perm(d7, d6, 0x05040100u);
  L.u[0] = __builtin_amdgcn_perm(d1, d0, 0x07060302u);  // hi16 halves -> lo frag
  L.u[1] = __builtin_amdgcn_perm(d3, d2, 0x07060302u);
  L.u[2] = __builtin_amdgcn_perm(d5, d4, 0x07060302u);
  L.u[3] = __builtin_amdgcn_perm(d7, d6, 0x07060302u);
  hi = H.v; lo = L.v;
}

// pack 8 floats (l-order) -> 4 RNE-bf16-pair dwords, one b128 LDS write
__device__ __forceinline__ void pack_write(const float* f, u16* wb) {
  u32 pk[4];
  #pragma unroll
  for (int i = 0; i < 4; ++i) {
    u32 a = __float_as_uint(f[2 * i]);     a += 0x7fffu + ((a >> 16) & 1u);
    u32 c = __float_as_uint(f[2 * i + 1]); c += 0x7fffu + ((c >> 16) & 1u);
    pk[i] = __builtin_amdgcn_perm(c, a, 0x07060302u);   // {a.hi16, c.hi16} -> l-order
  }
  *(uint4*)wb = *(const uint4*)pk;
}

// ---------------- fused main: per (b,h) Toeplitz GEMM ----------------
// Block: 512 thr = 8 waves = 2 j-positions x 4 K-quarters. Wave tile 128j x 64d.
// Grid: 256 (8 j-tiles of 256 x 32 bh), XCD-swizzled.
__global__ __launch_bounds__(512, 2) void toeplitz_fused(
    const float* __restrict__ v, const u32* __restrict__ upk, float* __restrict__ out)
{
  __shared__ __align__(16) u32 tab[4096];            // 16 KB packed Toeplitz table
  __shared__ __align__(16) u16 vt[4][64][32];        // 16 KB [kquarter][d][l] single bf16 plane
  __shared__ __align__(16) float red[3][2][4][64][4]; // 24 KB cross-quarter reduce (lane-major)

  const int tid  = threadIdx.x;
  const int lane = tid & 63;
  const int wv   = tid >> 6;      // 0..7
  const int p    = wv & 1;        // j-position (0/1 -> +0/+128)
  const int q    = wv >> 1;       // K-quarter: l in [q*512, q*512+512)
  const int m    = lane & 15;     // MFMA row/col within fragment
  const int g4   = lane >> 4;     // MFMA k-group 0..3

  // XCD-aware bijective swizzle: 4 (b,h) panels per XCD (4 MB fp32 = L2)
  const int lin = blockIdx.x;     // 0..255
  const int xcd = lin & 7;
  const int sl  = lin >> 3;       // 0..31
  const int bh  = (xcd << 2) | (sl >> 3);
  const int jt  = sl & 7;         // j-tile (256 rows)
  const int b = bh >> 4, h = bh & 15;

  // stage Toeplitz table (covered by first barrier)
  {
    const u32* src = upk + h * 4096;
    *(uint4*)&tab[tid * 4]        = *(const uint4*)&src[tid * 4];
    *(uint4*)&tab[2048 + tid * 4] = *(const uint4*)&src[2048 + tid * 4];
  }

  // ---- staging geometry (conflict-free by construction) ----
  // wave (p,q) stages quarter q, d-stripes p*32+{0,16}; thread: d=stripe+(lane>>2), l-granule=lane&3.
  // LDS write addr = lane*16 + const  -> consecutive 1024 B per wave per rep.
  const int sg = lane & 3;
  const int dd = lane >> 2;
  const int d0 = p * 32 + dd;
  u16* wb_r0 = &vt[q][d0][sg * 8];
  u16* wb_r1 = &vt[q][d0 + 16][sg * 8];
  // global: v[((b*S + l)*H + h)*D + d], l = q*512 + s*32 + sg*8 + i
  const float* gsrc = v + ((size_t)(b * SS + q * 512 + sg * 8)) * (HH * DD) + h * DD + d0;
  // l step = 1024 floats; rep1 = +16 d; tile step = 32*1024 floats.

  // ---- B-frag read: lane (m,g4) reads vt[q][nf*16+m][g4*8..+8]; addr = lane'*16 consecutive ----
  const u16* brd = &vt[q][m][g4 * 8];

  // ---- A (Toeplitz) base: t = 2047 - j + l ----
  const int jb = jt * 256 + p * 128;
  const int tA = 2047 - jb - m + 8 * g4 + q * 512;

  // ---- prologue: stage tile 0 ----
  float rF[16];
  {
    #pragma unroll
    for (int i = 0; i < 8; ++i) rF[i]     = gsrc[i * 1024];
    #pragma unroll
    for (int i = 0; i < 8; ++i) rF[8 + i] = gsrc[16 + i * 1024];
    pack_write(&rF[0], wb_r0);
    pack_write(&rF[8], wb_r1);
  }

  f32x4 acc[8][4];
  #pragma unroll
  for (int i = 0; i < 8; ++i)
    #pragma unroll
    for (int j = 0; j < 4; ++j)
      acc[i][j] = (f32x4)(0.0f);

  __syncthreads();   // tab + vt(tile0) visible

  // initial A-frags (tab written by all threads -> must be after barrier)
  bf16x8 Ahi[8], Alo[8];
  #pragma unroll
  for (int jf = 0; jf < 8; ++jf)
    load_afrag(tab, tA - 16 * jf, Ahi[jf], Alo[jf]);

  // ---- main loop: 16 K-tiles of 32 l per quarter; 2 barriers/tile ----
  for (int s = 0; s < 16; ++s) {
    // issue next tile's global loads early (consumed after next barrier; ~2500 cyc to cover)
    if (s < 15) {
      const float* gs = gsrc + (size_t)(s + 1) * 32768;
      #pragma unroll
      for (int i = 0; i < 8; ++i) rF[i]     = gs[i * 1024];
      #pragma unroll
      for (int i = 0; i < 8; ++i) rF[8 + i] = gs[16 + i * 1024];
    }

    // compute tile s: 4 B-frags, 64 MFMA
    #pragma unroll
    for (int nf = 0; nf < 4; ++nf) {
      bf16x8 bb = *(const bf16x8*)(brd + nf * 512);
      #pragma unroll
      for (int jf = 0; jf < 8; ++jf) {
        acc[jf][nf] = __builtin_amdgcn_mfma_f32_16x16x32_bf16(Ahi[jf], bb, acc[jf][nf], 0, 0, 0);
        acc[jf][nf] = __builtin_amdgcn_mfma_f32_16x16x32_bf16(Alo[jf], bb, acc[jf][nf], 0, 0, 0);
      }
    }

    // Toeplitz shift-reuse for tile s+1: frag(jf) <- frag(jf-2); 2 fresh pairs
    if (s < 15) {
      Ahi[7] = Ahi[5]; Alo[7] = Alo[5];
      Ahi[6] = Ahi[4]; Alo[6] = Alo[4];
      Ahi[5] = Ahi[3]; Alo[5] = Alo[3];
      Ahi[4] = Ahi[2]; Alo[4] = Alo[2];
      Ahi[3] = Ahi[1]; Alo[3] = Alo[1];
      Ahi[2] = Ahi[0]; Alo[2] = Alo[0];
      const int tn = tA + 32 * (s + 1);
      load_afrag(tab, tn,      Ahi[0], Alo[0]);
      load_afrag(tab, tn - 16, Ahi[1], Alo[1]);
    }

    __syncthreads();   // all waves done reading vt(s)
    if (s < 15) {
      pack_write(&rF[0], wb_r0);
      pack_write(&rF[8], wb_r1);
    }
    __syncthreads();   // vt(s+1) visible
  }

  // ---- cross-quarter reduction + store: q=1,2,3 -> red; q=0 sums + writes ----
  float* obase = out + ((size_t)b * SS + jb) * (HH * DD) + h * DD + m;
  #pragma unroll
  for (int jf = 0; jf < 8; ++jf) {
    if (q) {
      #pragma unroll
      for (int nf = 0; nf < 4; ++nf)
        *(f32x4*)&red[q - 1][p][nf][lane][0] = acc[jf][nf];
    }
    __syncthreads();
    if (!q) {
      #pragma unroll
      for (int nf = 0; nf < 4; ++nf) {
        f32x4 c = acc[jf][nf];
        c += *(const f32x4*)&red[0][p][nf][lane][0];
        c += *(const f32x4*)&red[1][p][nf][lane][0];
        c += *(const f32x4*)&red[2][p][nf][lane][0];
        #pragma unroll
        for (int qi = 0; qi < 4; ++qi) {
          int j = jf * 16 + g4 * 4 + qi;          // relative to jb
          obase[(size_t)j * (HH * DD) + nf * 16] = c[qi];
        }
      }
    }
    __syncthreads();
  }
}

// ---------------- fallback (tiny ws): direct fp32 VALU, correct but slow ----------------
__global__ __launch_bounds__(256) void fallback_k(const float* __restrict__ v,
                                                  const float* __restrict__ w,
                                                  float* __restrict__ out)
{
  __shared__ float wrow[SS];
  const int t = threadIdx.x;
  const int j0 = blockIdx.x * 64;
  const int bh = blockIdx.y;
  const int b = bh >> 4, h = bh & 15;
  for (int i = t; i < SS; i += 256) wrow[i] = w[h * SS + i];
  __syncthreads();
  const int jj = t >> 6, d = t & 63;
  float acc[16];
  #pragma unroll
  for (int r = 0; r < 16; ++r) acc[r] = 0.f;
  for (int l = 0; l < SS; ++l) {
    float vv = v[(((size_t)b * SS + l) * HH + h) * DD + d];
    #pragma unroll
    for (int r = 0; r < 16; ++r) {
      int dj = l - (j0 + jj * 16 + r);
      acc[r] += wrow[dj < 0 ? -dj : dj] * vv;
    }
  }
  #pragma unroll
  for (int r = 0; r < 16; ++r)
    out[(((size_t)b * SS + (j0 + jj * 16 + r)) * HH + h) * DD + d] = acc[r];
}

extern "C" void kernel_launch(void* const* d_in, const int* in_sizes, int n_in,
                              void* d_out, int out_size, void* d_ws, size_t ws_size,
                              hipStream_t stream)
{
  const float* v = (const float*)d_in[0];
  const float* w = (const float*)d_in[1];
  float* out = (float*)d_out;
  const size_t need = (size_t)HH * 4096 * 4;   // 256 KB packed Toeplitz table
  if (ws_size >= need) {
    u32* upk = (u32*)d_ws;
    prep_w<<<dim3(16, 16), 256, 0, stream>>>(w, upk);
    toeplitz_fused<<<dim3(256), 512, 0, stream>>>(v, upk, out);
  } else {
    fallback_k<<<dim3(32, 32), 256, 0, stream>>>(v, w, out);
  }
}